// Round 3
// baseline (1861.314 us; speedup 1.0000x reference)
//
#include <hip/hip_runtime.h>
#include <hip/hip_bf16.h>

// ---------------- problem constants ----------------
#define S_TOKENS 16384   // B*N
#define DMODEL   1024
#define NEXP     8
#define HFF      4096
#define CAP      2560    // int(S*1.25/E)
#define OUT_TOTAL (S_TOKENS * DMODEL + 1)

typedef __attribute__((ext_vector_type(8))) short bf16x8;
typedef __attribute__((ext_vector_type(4))) float f32x4;

__device__ inline float bf2f(unsigned short u) {
    union { unsigned int i; float f; } v; v.i = ((unsigned int)u) << 16; return v.f;
}
__device__ inline unsigned short f2bf(float f) {
    __hip_bfloat16 h = __float2bfloat16(f);
    return *reinterpret_cast<unsigned short*>(&h);
}
// dtype-flexible load: f32i=1 -> float*, else bf16(ushort)*
__device__ inline float ldg(const void* p, size_t i, int f32i) {
    return f32i ? ((const float*)p)[i] : bf2f(((const ushort*)p)[i]);
}
__device__ inline float gelu_tanh(float x) {
    float u = 0.7978845608028654f * (x + 0.044715f * x * x * x);
    return 0.5f * x * (1.0f + tanhf(u));
}
__device__ inline void lds16(const void* g, void* l) {
    __builtin_amdgcn_global_load_lds((const __attribute__((address_space(1))) unsigned int*)g,
                                     (__attribute__((address_space(3))) unsigned int*)l, 16, 0, 0);
}

// ---------------- dtype detection ----------------
// If x is bf16, low ushort of each 2-ushort pair is a bf16 value of N(0,1): exp field in sane band.
// If x is f32, low ushort is random mantissa bits: exp field uniform -> ~16% in band.
__global__ void detect_kernel(const ushort* __restrict__ xus, int* __restrict__ flag) {
    const int lane = threadIdx.x;  // 64
    int cnt = 0;
#pragma unroll
    for (int j = 0; j < 16; j++) {
        int p = lane * 16 + j;
        int eb = (xus[2 * p] >> 7) & 0xFF;
        cnt += (eb >= 100 && eb <= 140) ? 1 : 0;
    }
#pragma unroll
    for (int off = 32; off > 0; off >>= 1) cnt += __shfl_down(cnt, off, 64);
    if (lane == 0) flag[0] = (cnt < 512) ? 1 : 0;   // 1 = f32, 0 = bf16
}

// ---------------- zero the output ----------------
__global__ __launch_bounds__(256) void zero_kernel(void* __restrict__ out, const int* __restrict__ dflag) {
    const int f32i = *dflag;
    for (size_t i = (size_t)blockIdx.x * 256 + threadIdx.x; i < OUT_TOTAL; i += (size_t)gridDim.x * 256) {
        if (f32i) ((float*)out)[i] = 0.f; else ((ushort*)out)[i] = 0;
    }
}

// ---------------- x -> bf16 copy ----------------
__global__ __launch_bounds__(256) void convx_kernel(const void* __restrict__ x, const int* __restrict__ dflag,
                                                    ushort* __restrict__ xb) {
    const int f32i = *dflag;
    for (size_t i = (size_t)blockIdx.x * 256 + threadIdx.x; i < (size_t)S_TOKENS * DMODEL;
         i += (size_t)gridDim.x * 256)
        xb[i] = f32i ? f2bf(((const float*)x)[i]) : ((const ushort*)x)[i];
}

// ---------------- gating ----------------
__global__ __launch_bounds__(256) void gate_kernel(const void* __restrict__ x, const void* __restrict__ Wg,
                                                   const int* __restrict__ dflag,
                                                   float* __restrict__ gate1, float* __restrict__ gate2,
                                                   int* __restrict__ idx1, int* __restrict__ idx2,
                                                   float* __restrict__ bsum) {
    __shared__ float wgs[DMODEL * NEXP];   // 32 KB
    __shared__ float gsh[4][NEXP];
    const int t = threadIdx.x;
    const int f32i = *dflag;
    for (int i = t; i < DMODEL * NEXP; i += 256) wgs[i] = ldg(Wg, i, f32i);
    __syncthreads();
    const int wave = t >> 6, lane = t & 63;
    const int s = blockIdx.x * 4 + wave;
    float acc[NEXP];
#pragma unroll
    for (int e = 0; e < NEXP; e++) acc[e] = 0.f;
#pragma unroll
    for (int i = 0; i < 16; i++) {
        int d = i * 64 + lane;
        float xv = ldg(x, (size_t)s * DMODEL + d, f32i);
        const float* w = &wgs[d * NEXP];
#pragma unroll
        for (int e = 0; e < NEXP; e++) acc[e] += xv * w[e];
    }
#pragma unroll
    for (int off = 32; off > 0; off >>= 1)
#pragma unroll
        for (int e = 0; e < NEXP; e++) acc[e] += __shfl_down(acc[e], off, 64);
    if (lane == 0) {
        float mx = acc[0];
#pragma unroll
        for (int e = 1; e < NEXP; e++) mx = fmaxf(mx, acc[e]);
        float p[NEXP], se = 0.f;
#pragma unroll
        for (int e = 0; e < NEXP; e++) { p[e] = __expf(acc[e] - mx); se += p[e]; }
        float inv = 1.0f / se;
#pragma unroll
        for (int e = 0; e < NEXP; e++) p[e] *= inv;
        int i1 = 0; float g1v = p[0];
#pragma unroll
        for (int e = 1; e < NEXP; e++) if (p[e] > g1v) { g1v = p[e]; i1 = e; }
        int i2 = -1; float g2v = -1.0f;
#pragma unroll
        for (int e = 0; e < NEXP; e++) if (e != i1 && p[e] > g2v) { g2v = p[e]; i2 = e; }
        gate1[s] = g1v; gate2[s] = g2v; idx1[s] = i1; idx2[s] = i2;
#pragma unroll
        for (int e = 0; e < NEXP; e++) gsh[wave][e] = p[e];
    }
    __syncthreads();
    if (t < NEXP) bsum[blockIdx.x * NEXP + t] = gsh[0][t] + gsh[1][t] + gsh[2][t] + gsh[3][t];
}

// ---------------- capacity scan (1 wave, exact sequential semantics) + loss ----------------
__global__ void scan_kernel(const int* __restrict__ idx1, const int* __restrict__ idx2,
                            const float* __restrict__ bsum, const int* __restrict__ dflag,
                            int* __restrict__ p1i, int* __restrict__ p2i,
                            int* __restrict__ rowmap, void* __restrict__ out) {
    const int lane = threadIdx.x;   // 64
    const unsigned long long below = (1ull << lane) - 1ull;
    for (int i = lane; i < NEXP * CAP; i += 64) rowmap[i] = -1;
    int base[NEXP];
#pragma unroll
    for (int e = 0; e < NEXP; e++) base[e] = 0;
    for (int it = 0; it < S_TOKENS / 64; it++) {
        int s = it * 64 + lane;
        int id = idx1[s];
        int pos = 0;
#pragma unroll
        for (int e = 0; e < NEXP; e++) {
            unsigned long long m = __ballot(id == e);
            if (id == e) pos = base[e] + __popcll(m & below);
            base[e] += __popcll(m);
        }
        if (pos < CAP) { p1i[s] = pos; rowmap[id * CAP + pos] = s; }
        else p1i[s] = -1;
    }
    int count1[NEXP], base2[NEXP];
#pragma unroll
    for (int e = 0; e < NEXP; e++) {
        count1[e] = base[e];
        base2[e] = base[e] < CAP ? base[e] : CAP;   // used1 = min(count1, C)
    }
    for (int it = 0; it < S_TOKENS / 64; it++) {
        int s = it * 64 + lane;
        int id = idx2[s];
        int pos = 0;
#pragma unroll
        for (int e = 0; e < NEXP; e++) {
            unsigned long long m = __ballot(id == e);
            if (id == e) pos = base2[e] + __popcll(m & below);
            base2[e] += __popcll(m);
        }
        if (pos < CAP) { p2i[s] = pos; rowmap[id * CAP + pos] = s; }
        else p2i[s] = -1;
    }
    float msum[NEXP];
#pragma unroll
    for (int e = 0; e < NEXP; e++) msum[e] = 0.f;
    for (int b = lane; b < S_TOKENS / 4; b += 64)
#pragma unroll
        for (int e = 0; e < NEXP; e++) msum[e] += bsum[b * NEXP + e];
#pragma unroll
    for (int off = 32; off > 0; off >>= 1)
#pragma unroll
        for (int e = 0; e < NEXP; e++) msum[e] += __shfl_down(msum[e], off, 64);
    if (lane == 0) {
        float l = 0.f;
#pragma unroll
        for (int e = 0; e < NEXP; e++)
            l += (msum[e] / (float)S_TOKENS) * ((float)count1[e] / (float)S_TOKENS);
        float L = 0.08f * l;   // 0.01 * mean(me*ce) * E*E
        if (*dflag) ((float*)out)[(size_t)S_TOKENS * DMODEL] = L;
        else        ((ushort*)out)[(size_t)S_TOKENS * DMODEL] = f2bf(L);
    }
}

// ---------------- transpose + convert: dst[c][r] (bf16) = src[srcBase + r*srcStride + c] ----------------
__global__ __launch_bounds__(256) void transpose_conv(const void* __restrict__ src, ushort* __restrict__ dst,
                                                      const int* __restrict__ dflag,
                                                      long srcBase, int srcStride, int dstStride) {
    __shared__ ushort tile[64][68];
    const int f32i = *dflag;
    const int c0 = blockIdx.x * 64, r0 = blockIdx.y * 64;
    const int tx = threadIdx.x & 15, ty = threadIdx.x >> 4;
#pragma unroll
    for (int k = 0; k < 4; k++) {
        int row = ty + 16 * k;
        size_t b = (size_t)srcBase + (size_t)(r0 + row) * srcStride + c0 + tx * 4;
#pragma unroll
        for (int j = 0; j < 4; j++) tile[row][tx * 4 + j] = f2bf(ldg(src, b + j, f32i));
    }
    __syncthreads();
#pragma unroll
    for (int k = 0; k < 4; k++) {
        int orow = ty + 16 * k;
        ushort4 v;
        v.x = tile[tx * 4 + 0][orow];
        v.y = tile[tx * 4 + 1][orow];
        v.z = tile[tx * 4 + 2][orow];
        v.w = tile[tx * 4 + 3][orow];
        *(ushort4*)(dst + (size_t)(c0 + orow) * dstStride + r0 + tx * 4) = v;
    }
}

// ---------------- GEMM1: h[2560, NC] = GELU(gather(xb)[2560,1024] @ T[NC,1024]^T + b1slice) ----------------
template<int NC>
__global__ __launch_bounds__(256) void gemm1_kernel(const ushort* __restrict__ xb,
                                                    const int* __restrict__ rowmapE,
                                                    const ushort* __restrict__ T,
                                                    const void* __restrict__ b1, long biasBase,
                                                    const int* __restrict__ dflag,
                                                    ushort* __restrict__ hout) {
    __shared__ ushort lA[128 * 32];
    __shared__ ushort lB[128 * 32];
    const int t = threadIdx.x;
    const int w = t >> 6, lane = t & 63;
    const int n0 = blockIdx.x * 128, m0 = blockIdx.y * 128;
    const int wr = w >> 1, wc = w & 1;
    const int l15 = lane & 15, quad = lane >> 4;

    int arow[2];
#pragma unroll
    for (int it = 0; it < 2; it++) {
        int r = (it * 2048 + w * 512 + lane * 8) >> 5;
        int rm = rowmapE[m0 + r];
        arow[it] = rm < 0 ? 0 : rm;
    }

    f32x4 acc[4][4];
#pragma unroll
    for (int i = 0; i < 4; i++)
#pragma unroll
        for (int j = 0; j < 4; j++) acc[i][j] = (f32x4){0.f, 0.f, 0.f, 0.f};

    for (int k0 = 0; k0 < DMODEL; k0 += 32) {
        __syncthreads();
#pragma unroll
        for (int it = 0; it < 2; it++) {
            int f = it * 2048 + w * 512 + lane * 8;
            int r = f >> 5, kk = f & 31;
            lds16(xb + (size_t)arow[it] * DMODEL + k0 + kk, &lA[it * 2048 + w * 512]);
            lds16(T + (size_t)(n0 + r) * DMODEL + k0 + kk, &lB[it * 2048 + w * 512]);
        }
        __syncthreads();
        bf16x8 af[4], bfr[4];
#pragma unroll
        for (int i = 0; i < 4; i++) af[i] = *(const bf16x8*)&lA[(wr * 64 + i * 16 + l15) * 32 + quad * 8];
#pragma unroll
        for (int j = 0; j < 4; j++) bfr[j] = *(const bf16x8*)&lB[(wc * 64 + j * 16 + l15) * 32 + quad * 8];
#pragma unroll
        for (int i = 0; i < 4; i++)
#pragma unroll
            for (int j = 0; j < 4; j++)
                acc[i][j] = __builtin_amdgcn_mfma_f32_16x16x32_bf16(af[i], bfr[j], acc[i][j], 0, 0, 0);
    }
    const int f32i = *dflag;
    float bv[4];
#pragma unroll
    for (int j = 0; j < 4; j++) bv[j] = ldg(b1, biasBase + n0 + wc * 64 + j * 16 + l15, f32i);
#pragma unroll
    for (int i = 0; i < 4; i++) {
        int row0 = m0 + wr * 64 + i * 16 + quad * 4;
#pragma unroll
        for (int j = 0; j < 4; j++) {
            int col = n0 + wc * 64 + j * 16 + l15;
#pragma unroll
            for (int r = 0; r < 4; r++)
                hout[(size_t)(row0 + r) * NC + col] = f2bf(gelu_tanh(acc[i][j][r] + bv[j]));
        }
    }
}

// ---------------- GEMM2: eoTile = h[2560,KC] @ T2[1024,KC]^T ; scatter-add w*(eo+b2) into out ----------------
template<int KC>
__global__ __launch_bounds__(256) void gemm2_kernel(const ushort* __restrict__ h,
                                                    const ushort* __restrict__ T2,
                                                    const void* __restrict__ b2, long b2Base,
                                                    const int* __restrict__ dflag,
                                                    const int* __restrict__ rowmapE,
                                                    const int* __restrict__ idx1,
                                                    const int* __restrict__ p1i, const int* __restrict__ p2i,
                                                    const float* __restrict__ gate1, const float* __restrict__ gate2,
                                                    int expert, int addB2, void* __restrict__ out) {
    __shared__ ushort lA[128 * 32];
    __shared__ ushort lB[128 * 32];
    const int t = threadIdx.x;
    const int w = t >> 6, lane = t & 63;
    const int n0 = blockIdx.x * 128, m0 = blockIdx.y * 128;
    const int wr = w >> 1, wc = w & 1;
    const int l15 = lane & 15, quad = lane >> 4;

    f32x4 acc[4][4];
#pragma unroll
    for (int i = 0; i < 4; i++)
#pragma unroll
        for (int j = 0; j < 4; j++) acc[i][j] = (f32x4){0.f, 0.f, 0.f, 0.f};

    for (int k0 = 0; k0 < KC; k0 += 32) {
        __syncthreads();
#pragma unroll
        for (int it = 0; it < 2; it++) {
            int f = it * 2048 + w * 512 + lane * 8;
            int r = f >> 5, kk = f & 31;
            lds16(h  + (size_t)(m0 + r) * KC + k0 + kk, &lA[it * 2048 + w * 512]);
            lds16(T2 + (size_t)(n0 + r) * KC + k0 + kk, &lB[it * 2048 + w * 512]);
        }
        __syncthreads();
        bf16x8 af[4], bfr[4];
#pragma unroll
        for (int i = 0; i < 4; i++) af[i] = *(const bf16x8*)&lA[(wr * 64 + i * 16 + l15) * 32 + quad * 8];
#pragma unroll
        for (int j = 0; j < 4; j++) bfr[j] = *(const bf16x8*)&lB[(wc * 64 + j * 16 + l15) * 32 + quad * 8];
#pragma unroll
        for (int i = 0; i < 4; i++)
#pragma unroll
            for (int j = 0; j < 4; j++)
                acc[i][j] = __builtin_amdgcn_mfma_f32_16x16x32_bf16(af[i], bfr[j], acc[i][j], 0, 0, 0);
    }
    const int f32i = *dflag;
    float b2v[4];
#pragma unroll
    for (int j = 0; j < 4; j++) b2v[j] = addB2 ? ldg(b2, b2Base + n0 + wc * 64 + j * 16 + l15, f32i) : 0.f;
#pragma unroll
    for (int i = 0; i < 4; i++) {
#pragma unroll
        for (int r = 0; r < 4; r++) {
            int row = m0 + wr * 64 + i * 16 + quad * 4 + r;
            int s = rowmapE[row];
            if (s < 0) continue;
            float g1 = gate1[s], g2 = gate2[s];
            float k1 = (p1i[s] >= 0) ? 1.f : 0.f, k2 = (p2i[s] >= 0) ? 1.f : 0.f;
            float denom = g1 * k1 + g2 * k2 + 1e-9f;
            float wgt = ((idx1[s] == expert) ? g1 : g2) / denom;
            size_t obase = (size_t)s * DMODEL;
#pragma unroll
            for (int j = 0; j < 4; j++) {
                int col = n0 + wc * 64 + j * 16 + l15;
                float contrib = wgt * (acc[i][j][r] + b2v[j]);
                size_t oi = obase + col;
                if (f32i) { float* po = (float*)out; po[oi] += contrib; }
                else { ushort* po = (ushort*)out; po[oi] = f2bf(bf2f(po[oi]) + contrib); }
            }
        }
    }
}

// ---------------- pipeline ----------------
template<int HC>
static void run_moe(const void* x, const void* Wg, const void* W1, const void* b1,
                    const void* W2, const void* b2, void* out, char* ws, hipStream_t stream) {
    int*   flag   = (int*)ws;
    int*   rowmap = (int*)(ws + 256);
    float* gate1  = (float*)(ws + 82176);
    float* gate2  = (float*)(ws + 147712);
    int*   idx1   = (int*)(ws + 213248);
    int*   idx2   = (int*)(ws + 278784);
    int*   p1i    = (int*)(ws + 344320);
    int*   p2i    = (int*)(ws + 409856);
    float* bsum   = (float*)(ws + 475392);       // +131072 -> 606464
    ushort* xb    = (ushort*)(ws + 655360);      // 33,554,432 B
    ushort* h     = (ushort*)(ws + 655360 + 33554432);                       // 2560*HC*2
    ushort* T     = (ushort*)(ws + 655360 + 33554432 + (size_t)2560 * HC * 2); // 1024*HC*2

    detect_kernel<<<dim3(1), 64, 0, stream>>>((const ushort*)x, flag);
    zero_kernel<<<dim3(16384), 256, 0, stream>>>(out, flag);
    convx_kernel<<<dim3(8192), 256, 0, stream>>>(x, flag, xb);
    gate_kernel<<<dim3(S_TOKENS / 4), 256, 0, stream>>>(x, Wg, flag, gate1, gate2, idx1, idx2, bsum);
    scan_kernel<<<dim3(1), 64, 0, stream>>>(idx1, idx2, bsum, flag, p1i, p2i, rowmap, out);

    for (int e = 0; e < NEXP; e++) {
        for (int c = 0; c < HFF / HC; c++) {
            const long hoff = (long)c * HC;
            // T <- W1[e][:, hoff:hoff+HC]^T  => [HC][1024]
            transpose_conv<<<dim3(HC / 64, DMODEL / 64), 256, 0, stream>>>(
                W1, T, flag, (long)e * DMODEL * HFF + hoff, HFF, DMODEL);
            gemm1_kernel<HC><<<dim3(HC / 128, CAP / 128), 256, 0, stream>>>(
                xb, rowmap + e * CAP, T, b1, (long)e * HFF + hoff, flag, h);
            // T <- W2[e][hoff:hoff+HC, :]^T  => [1024][HC]
            transpose_conv<<<dim3(DMODEL / 64, HC / 64), 256, 0, stream>>>(
                W2, T, flag, (long)e * HFF * DMODEL + hoff * DMODEL, DMODEL, HC);
            gemm2_kernel<HC><<<dim3(DMODEL / 128, CAP / 128), 256, 0, stream>>>(
                h, T, b2, (long)e * DMODEL, flag, rowmap + e * CAP,
                idx1, p1i, p2i, gate1, gate2, e, c == 0 ? 1 : 0, out);
        }
    }
}

// ---------------- launcher ----------------
extern "C" void kernel_launch(void* const* d_in, const int* in_sizes, int n_in,
                              void* d_out, int out_size, void* d_ws, size_t ws_size,
                              hipStream_t stream) {
    const void* x  = d_in[0];
    const void* Wg = d_in[1];
    const void* W1 = d_in[2];
    const void* b1 = d_in[3];
    const void* W2 = d_in[4];
    const void* b2 = d_in[5];
    char* ws = (char*)d_ws;

    // footprints: HC=4096 -> 63.6 MB, 2048 -> 48.9 MB, 1024 -> 41.5 MB, 512 -> 37.9 MB
    if (ws_size >= 64000000ull)      run_moe<4096>(x, Wg, W1, b1, W2, b2, d_out, ws, stream);
    else if (ws_size >= 49000000ull) run_moe<2048>(x, Wg, W1, b1, W2, b2, d_out, ws, stream);
    else if (ws_size >= 42000000ull) run_moe<1024>(x, Wg, W1, b1, W2, b2, d_out, ws, stream);
    else                             run_moe<512>(x, Wg, W1, b1, W2, b2, d_out, ws, stream);
}